// Round 19
// baseline (226.721 us; speedup 1.0000x reference)
//
#include <hip/hip_runtime.h>
#include <hip/hip_bf16.h>
#include <math.h>

#define CH 128
#define LAYERS 3
#define NEG_SLOPE 0.2f
#define EPS_D 1e-16f
#define NBUCK_MAX 512
#define BIN_CHUNK 8192
#define PAIR_STRIDE 4608   // fixed per-bucket region; Binomial(1.6M,1/391) max ~4320

typedef __attribute__((ext_vector_type(8))) short bf16x8;
typedef __attribute__((ext_vector_type(4))) float f32x4;
typedef __attribute__((ext_vector_type(2))) float f32x2;

__device__ __forceinline__ float leaky(float e) { return e > 0.f ? e : NEG_SLOPE * e; }
__device__ __forceinline__ float sigm(float x) { return 1.f / (1.f + __expf(-x)); }

__device__ __forceinline__ unsigned bf16rne(float f) {
    unsigned u = __float_as_uint(f);
    return (u + 0x7fffu + ((u >> 16) & 1u)) >> 16;
}
__device__ __forceinline__ unsigned pack2(float f0, float f1) {
    return bf16rne(f0) | (bf16rne(f1) << 16);
}
__device__ __forceinline__ float bf16tof(unsigned short v) {
    return __uint_as_float(((unsigned)v) << 16);
}

// ---------------- CSR build (bucketed, padded col regions; bucket b = dst>>8) ---------------
__global__ __launch_bounds__(256) void bin_k(const int* __restrict__ EI,
                                             int* __restrict__ bcursor,
                                             unsigned* __restrict__ pairs,
                                             int ne, int nbuck) {
    __shared__ int hist[NBUCK_MAX];
    __shared__ int base[NBUCK_MAX];
    const int t = threadIdx.x;
    const int e0 = blockIdx.x * BIN_CHUNK;
    const int e1 = min(e0 + BIN_CHUNK, ne);

    for (int i = t; i < nbuck; i += 256) hist[i] = 0;
    __syncthreads();
    for (int e = e0 + t; e < e1; e += 256)
        atomicAdd(&hist[EI[ne + e] >> 8], 1);
    __syncthreads();
    for (int i = t; i < nbuck; i += 256) {
        int c = hist[i];
        base[i] = (c > 0) ? (i * PAIR_STRIDE + atomicAdd(&bcursor[i], c)) : 0;
        hist[i] = 0;
    }
    __syncthreads();
    for (int e = e0 + t; e < e1; e += 256) {
        int src = EI[e], dst = EI[ne + e];
        int b = dst >> 8;
        int off = atomicAdd(&hist[b], 1);
        pairs[base[b] + off] = ((unsigned)src << 8) | (unsigned)(dst & 255);
    }
}

// per-bucket count+scan -> rowbeg/rowend (padded positions), then scatter col
__global__ __launch_bounds__(256) void bscat_k(const int* __restrict__ bcursor,
                                               const unsigned* __restrict__ pairs,
                                               int* __restrict__ col,
                                               int* __restrict__ rowbeg,
                                               int* __restrict__ rowend, int n) {
    __shared__ int hist[256];
    __shared__ int cur[256];
    __shared__ int wsum[4];
    const int b = blockIdx.x;
    const int node0 = b << 8;
    const int t = threadIdx.x;
    const int lane = t & 63, w = t >> 6;

    hist[t] = 0;
    __syncthreads();
    const int pbase = b * PAIR_STRIDE;
    const int tot = bcursor[b];
    for (int i = t; i < tot; i += 256)
        atomicAdd(&hist[pairs[pbase + i] & 255u], 1);
    __syncthreads();

    int v = hist[t];
    int sc = v;
#pragma unroll
    for (int off = 1; off < 64; off <<= 1) {
        int x = __shfl_up(sc, off);
        if (lane >= off) sc += x;
    }
    if (lane == 63) wsum[w] = sc;
    __syncthreads();
    if (t == 0) {
        int a = 0;
#pragma unroll
        for (int j = 0; j < 4; j++) { int tmp = wsum[j]; wsum[j] = a; a += tmp; }
    }
    __syncthreads();
    int excl = sc - v + wsum[w];
    int node = node0 + t;
    int rp = pbase + excl;
    if (node < n) {
        rowbeg[node] = rp;
        rowend[node] = rp + v;
        cur[t] = rp;
    }
    __syncthreads();

    for (int i = t; i < tot; i += 256) {
        unsigned p = pairs[pbase + i];
        int pos = atomicAdd(&cur[p & 255u], 1);
        col[pos] = (int)(p >> 8);
    }
}

// ---------------- MFMA GEMM: H(fp8, permuted) = X @ W, fused s,d ----------------------------
// 256 nodes/block, 512 threads (8 waves), 2 row-groups per wave sharing B-fragments.
// WT row stride 136 shorts (272B, 16B-aligned) -> ONE ds_read_b128 per B-fragment
// (2-way bank alias = free, m136). XBF16: x rows are bf16 (intermediate layers).
template <int XBF16>
__global__ __launch_bounds__(512) void gemm_k(const void* __restrict__ Xv,
                                              const float* __restrict__ Wm,
                                              const float* __restrict__ asrc,
                                              const float* __restrict__ adst,
                                              unsigned* __restrict__ Hf8,
                                              float* __restrict__ s,
                                              float* __restrict__ d, int n) {
    __shared__ short WT[128 * 136];   // WT[c][k], row stride 136 shorts (16B-aligned rows)
    const int t = threadIdx.x;
    const int node0 = blockIdx.x * 256;

    unsigned* WT32 = (unsigned*)WT;
#pragma unroll
    for (int i = 0; i < 16; i++) {
        int item = i * 512 + t;
        int c = item & 127, k2 = item >> 7;
        float va = Wm[(2 * k2) * 128 + c];
        float vb = Wm[(2 * k2 + 1) * 128 + c];
        WT32[c * 68 + k2] = pack2(va, vb);
    }
    __syncthreads();

    const int lane = t & 63, w = t >> 6;
    const int lr = lane & 15, lg = lane >> 4;
    const int rowA = w * 16 + lr;
    const int nodeA0 = min(node0 + rowA, n - 1);
    const int nodeA1 = min(node0 + 128 + rowA, n - 1);

    f32x4 acc[2][8];
#pragma unroll
    for (int rs = 0; rs < 2; rs++)
#pragma unroll
        for (int ct = 0; ct < 8; ct++) acc[rs][ct] = (f32x4){0.f, 0.f, 0.f, 0.f};

#pragma unroll
    for (int kt = 0; kt < 4; kt++) {
        const int kb = kt * 32 + lg * 8;
        bf16x8 a0, a1;
        if (XBF16) {
            const unsigned short* xb = (const unsigned short*)Xv;
            a0 = *(const bf16x8*)&xb[(size_t)nodeA0 * CH + kb];
            a1 = *(const bf16x8*)&xb[(size_t)nodeA1 * CH + kb];
        } else {
            const float* xf = (const float*)Xv;
            const float4 fa = *(const float4*)&xf[(size_t)nodeA0 * CH + kb];
            const float4 fb = *(const float4*)&xf[(size_t)nodeA0 * CH + kb + 4];
            const float4 ga = *(const float4*)&xf[(size_t)nodeA1 * CH + kb];
            const float4 gb = *(const float4*)&xf[(size_t)nodeA1 * CH + kb + 4];
            a0[0] = (short)bf16rne(fa.x); a0[1] = (short)bf16rne(fa.y);
            a0[2] = (short)bf16rne(fa.z); a0[3] = (short)bf16rne(fa.w);
            a0[4] = (short)bf16rne(fb.x); a0[5] = (short)bf16rne(fb.y);
            a0[6] = (short)bf16rne(fb.z); a0[7] = (short)bf16rne(fb.w);
            a1[0] = (short)bf16rne(ga.x); a1[1] = (short)bf16rne(ga.y);
            a1[2] = (short)bf16rne(ga.z); a1[3] = (short)bf16rne(ga.w);
            a1[4] = (short)bf16rne(gb.x); a1[5] = (short)bf16rne(gb.y);
            a1[6] = (short)bf16rne(gb.z); a1[7] = (short)bf16rne(gb.w);
        }
#pragma unroll
        for (int ct = 0; ct < 8; ct++) {
            const int cc = ct * 16 + lr;
            bf16x8 bb = *(const bf16x8*)&WT[cc * 136 + kb];   // single b128 read
            acc[0][ct] = __builtin_amdgcn_mfma_f32_16x16x32_bf16(a0, bb, acc[0][ct], 0, 0, 0);
            acc[1][ct] = __builtin_amdgcn_mfma_f32_16x16x32_bf16(a1, bb, acc[1][ct], 0, 0, 0);
        }
    }

    float asv[8], adv[8];
#pragma unroll
    for (int ct = 0; ct < 8; ct++) { asv[ct] = asrc[ct * 16 + lr]; adv[ct] = adst[ct * 16 + lr]; }

#pragma unroll
    for (int rs = 0; rs < 2; rs++) {
#pragma unroll
        for (int r = 0; r < 4; r++) {
            const int orow = rs * 128 + w * 16 + lg * 4 + r;
            const int onode = node0 + orow;
            float ps = 0.f, pd = 0.f;
#pragma unroll
            for (int ct = 0; ct < 8; ct++) {
                float hv = acc[rs][ct][r];
                ps += hv * asv[ct];
                pd += hv * adv[ct];
            }
            if (onode < n) {
                int w0 = __builtin_amdgcn_cvt_pk_fp8_f32(acc[rs][0][r], acc[rs][1][r], 0, false);
                w0 = __builtin_amdgcn_cvt_pk_fp8_f32(acc[rs][2][r], acc[rs][3][r], w0, true);
                int w1 = __builtin_amdgcn_cvt_pk_fp8_f32(acc[rs][4][r], acc[rs][5][r], 0, false);
                w1 = __builtin_amdgcn_cvt_pk_fp8_f32(acc[rs][6][r], acc[rs][7][r], w1, true);
                uint2 q8; q8.x = (unsigned)w0; q8.y = (unsigned)w1;
                *(uint2*)&Hf8[(size_t)onode * 32 + lr * 2] = q8;
            }
#pragma unroll
            for (int off = 8; off >= 1; off >>= 1) {
                ps += __shfl_xor(ps, off);
                pd += __shfl_xor(pd, off);
            }
            if (lr == 0 && onode < n) { s[onode] = ps; d[onode] = pd; }
        }
    }
}

// ---------------- per-node online-softmax + aggregation + residual ---------------------------
// 4 nodes/wave, sequential order (R14/15 lesson), fp8 H, 4-edge unrolled gather (R18 lesson:
// 8-deep cost VGPR/occupancy more than its MLP bought), packed f32x2 accumulation.
__device__ __forceinline__ void acc_edge(f32x2* o2, const uint2 u, float we) {
    f32x2 w2 = {we, we};
    o2[0] += w2 * __builtin_amdgcn_cvt_pk_f32_fp8(u.x, false);
    o2[1] += w2 * __builtin_amdgcn_cvt_pk_f32_fp8(u.x, true);
    o2[2] += w2 * __builtin_amdgcn_cvt_pk_f32_fp8(u.y, false);
    o2[3] += w2 * __builtin_amdgcn_cvt_pk_f32_fp8(u.y, true);
}

template <int PBF16, int NBF16>
__global__ __launch_bounds__(256) void node_aggr_k(const int* __restrict__ rowbeg,
                                                   const int* __restrict__ rowend,
                                                   const int* __restrict__ col,
                                                   const float* __restrict__ s,
                                                   const float* __restrict__ d,
                                                   const unsigned* __restrict__ Hf8,
                                                   const float* __restrict__ bias,
                                                   const void* __restrict__ x_prev,
                                                   void* __restrict__ x_next, int n) {
    long g = (long)blockIdx.x * 256 + threadIdx.x;
    int node = (int)(g >> 4);
    if (node >= n) return;
    const int tid = threadIdx.x;
    const int sub = tid & 15;
    const int qbase = tid & 48;

    const int beg = rowbeg[node], end = rowend[node];
    const float dn = d[node];
    const float ev_self = leaky(s[node] + dn);

    float m = ev_self;
    float l = 0.f;
    f32x2 o2[4];
#pragma unroll
    for (int j = 0; j < 4; j++) o2[j] = (f32x2){0.f, 0.f};

    for (int j0 = beg; j0 < end; j0 += 16) {
        int cnt = min(16, end - j0);
        int srcv = 0;
        float ev = -INFINITY;
        if (sub < cnt) {
            srcv = col[j0 + sub];
            ev = leaky(s[srcv] + dn);
        }
        float bmax = ev;
#pragma unroll
        for (int off = 8; off >= 1; off >>= 1) bmax = fmaxf(bmax, __shfl_xor(bmax, off));
        float newm = fmaxf(m, bmax);
        float scale = __expf(m - newm);
        f32x2 sc2 = {scale, scale};
        l *= scale;
#pragma unroll
        for (int j = 0; j < 4; j++) o2[j] *= sc2;
        m = newm;
        float wv = (sub < cnt) ? __expf(ev - m) : 0.f;

        // 4-edge unrolled gather: full-exec shuffles with clamped indices (R6 lesson),
        // 4 loads in flight, tail edges duplicate last row with weight 0.
        for (int j = 0; j < cnt; j += 4) {
            int i1 = min(j + 1, cnt - 1), i2 = min(j + 2, cnt - 1), i3 = min(j + 3, cnt - 1);
            int se0 = __shfl(srcv, qbase + j);
            int se1 = __shfl(srcv, qbase + i1);
            int se2 = __shfl(srcv, qbase + i2);
            int se3 = __shfl(srcv, qbase + i3);
            float w0 = __shfl(wv, qbase + j);
            float w1 = __shfl(wv, qbase + i1);
            float w2 = __shfl(wv, qbase + i2);
            float w3 = __shfl(wv, qbase + i3);
            w1 = (j + 1 < cnt) ? w1 : 0.f;
            w2 = (j + 2 < cnt) ? w2 : 0.f;
            w3 = (j + 3 < cnt) ? w3 : 0.f;
            const uint2 u0 = *(const uint2*)&Hf8[(size_t)se0 * 32 + sub * 2];
            const uint2 u1 = *(const uint2*)&Hf8[(size_t)se1 * 32 + sub * 2];
            const uint2 u2 = *(const uint2*)&Hf8[(size_t)se2 * 32 + sub * 2];
            const uint2 u3 = *(const uint2*)&Hf8[(size_t)se3 * 32 + sub * 2];
            l += w0 + w1 + w2 + w3;
            acc_edge(o2, u0, w0);
            acc_edge(o2, u1, w1);
            acc_edge(o2, u2, w2);
            acc_edge(o2, u3, w3);
        }
    }

    // self loop (fp8, same as edges)
    float wself = __expf(ev_self - m);
    l += wself;
    const uint2 us = *(const uint2*)&Hf8[(size_t)node * 32 + sub * 2];
    acc_edge(o2, us, wself);

    float inv = 1.f / (l + EPS_D);
    const long rowb = (long)node * CH;
#pragma unroll
    for (int k = 0; k < 8; k++) {
        int c = k * 16 + sub;   // permuted: o2[k>>1][k&1] is channel k*16+sub
        float ov = o2[k >> 1][k & 1];
        float xv = PBF16 ? bf16tof(((const unsigned short*)x_prev)[rowb + c])
                         : ((const float*)x_prev)[rowb + c];
        float r = xv + sigm(ov * inv + bias[c]);
        if (NBF16)
            ((unsigned short*)x_next)[rowb + c] = (unsigned short)bf16rne(r);
        else
            ((float*)x_next)[rowb + c] = r;
    }
}

extern "C" void kernel_launch(void* const* d_in, const int* in_sizes, int n_in,
                              void* d_out, int out_size, void* d_ws, size_t ws_size,
                              hipStream_t stream) {
    const float* x_in = (const float*)d_in[0];
    const int* EI = (const int*)d_in[1];
    const float* Ws_all = (const float*)d_in[2];
    const float* asrc_all = (const float*)d_in[3];
    const float* adst_all = (const float*)d_in[4];
    const float* bias_all = (const float*)d_in[5];
    float* out = (float*)d_out;

    const int n = in_sizes[0] / CH;        // 100000
    const int ne = in_sizes[1] / 2;        // 1600000
    const long NC = (long)n * CH;
    const int nbuck = (n + 255) >> 8;

    unsigned* hf8 = (unsigned*)d_ws;                 // NC/4 u32 (fp8 H)
    float* s = (float*)(hf8 + NC / 4);
    float* dd = s + n;
    unsigned short* xb0 = (unsigned short*)(dd + n); // NC bf16
    unsigned short* xb1 = xb0 + NC;                  // NC bf16
    int* rowbeg = (int*)(xb1 + NC);
    int* rowend = rowbeg + n;
    int* bcursor = rowend + n;
    int* colv = bcursor + nbuck;                     // nbuck * PAIR_STRIDE
    unsigned* pairs = (unsigned*)(colv + nbuck * PAIR_STRIDE);  // nbuck * PAIR_STRIDE

    // --- CSR build (padded col regions; rowbeg/rowend from bscat) ---
    hipMemsetAsync(bcursor, 0, (size_t)nbuck * sizeof(int), stream);
    bin_k<<<(ne + BIN_CHUNK - 1) / BIN_CHUNK, 256, 0, stream>>>(EI, bcursor, pairs, ne, nbuck);
    bscat_k<<<nbuck, 256, 0, stream>>>(bcursor, pairs, colv, rowbeg, rowend, n);

    const int gG = (n + 255) / 256;
    const int gA = (int)(((long)n * 16 + 255) / 256);

    // layer 0: f32 in -> bf16 out
    gemm_k<0><<<gG, 512, 0, stream>>>(x_in, Ws_all, asrc_all, adst_all, hf8, s, dd, n);
    node_aggr_k<0, 1><<<gA, 256, 0, stream>>>(rowbeg, rowend, colv, s, dd, hf8,
                                              bias_all, x_in, xb0, n);
    // layer 1: bf16 in -> bf16 out
    gemm_k<1><<<gG, 512, 0, stream>>>(xb0, Ws_all + (size_t)CH * CH, asrc_all + CH,
                                      adst_all + CH, hf8, s, dd, n);
    node_aggr_k<1, 1><<<gA, 256, 0, stream>>>(rowbeg, rowend, colv, s, dd, hf8,
                                              bias_all + CH, xb0, xb1, n);
    // layer 2: bf16 in -> f32 out (final)
    gemm_k<1><<<gG, 512, 0, stream>>>(xb1, Ws_all + (size_t)2 * CH * CH, asrc_all + 2 * CH,
                                      adst_all + 2 * CH, hf8, s, dd, n);
    node_aggr_k<1, 0><<<gA, 256, 0, stream>>>(rowbeg, rowend, colv, s, dd, hf8,
                                              bias_all + 2 * CH, xb1, out, n);
}

// Round 20
// 221.319 us; speedup vs baseline: 1.0244x; 1.0244x over previous
//
#include <hip/hip_runtime.h>
#include <hip/hip_bf16.h>
#include <math.h>

#define CH 128
#define LAYERS 3
#define NEG_SLOPE 0.2f
#define EPS_D 1e-16f
#define NBUCK_MAX 512
#define BIN_CHUNK 8192
#define PAIR_STRIDE 4608   // fixed per-bucket region; Binomial(1.6M,1/391) max ~4320

typedef __attribute__((ext_vector_type(8))) short bf16x8;
typedef __attribute__((ext_vector_type(4))) float f32x4;
typedef __attribute__((ext_vector_type(2))) float f32x2;

__device__ __forceinline__ float leaky(float e) { return e > 0.f ? e : NEG_SLOPE * e; }
__device__ __forceinline__ float sigm(float x) { return 1.f / (1.f + __expf(-x)); }

__device__ __forceinline__ unsigned bf16rne(float f) {
    unsigned u = __float_as_uint(f);
    return (u + 0x7fffu + ((u >> 16) & 1u)) >> 16;
}
__device__ __forceinline__ unsigned pack2(float f0, float f1) {
    return bf16rne(f0) | (bf16rne(f1) << 16);
}
__device__ __forceinline__ float bf16tof(unsigned short v) {
    return __uint_as_float(((unsigned)v) << 16);
}

// ---------------- CSR build (bucketed, padded col regions; bucket b = dst>>8) ---------------
__global__ __launch_bounds__(256) void bin_k(const int* __restrict__ EI,
                                             int* __restrict__ bcursor,
                                             unsigned* __restrict__ pairs,
                                             int ne, int nbuck) {
    __shared__ int hist[NBUCK_MAX];
    __shared__ int base[NBUCK_MAX];
    const int t = threadIdx.x;
    const int e0 = blockIdx.x * BIN_CHUNK;
    const int e1 = min(e0 + BIN_CHUNK, ne);

    for (int i = t; i < nbuck; i += 256) hist[i] = 0;
    __syncthreads();
    for (int e = e0 + t; e < e1; e += 256)
        atomicAdd(&hist[EI[ne + e] >> 8], 1);
    __syncthreads();
    for (int i = t; i < nbuck; i += 256) {
        int c = hist[i];
        base[i] = (c > 0) ? (i * PAIR_STRIDE + atomicAdd(&bcursor[i], c)) : 0;
        hist[i] = 0;
    }
    __syncthreads();
    for (int e = e0 + t; e < e1; e += 256) {
        int src = EI[e], dst = EI[ne + e];
        int b = dst >> 8;
        int off = atomicAdd(&hist[b], 1);
        pairs[base[b] + off] = ((unsigned)src << 8) | (unsigned)(dst & 255);
    }
}

// per-bucket count+scan -> rowbeg/rowend (padded positions), then scatter col
__global__ __launch_bounds__(256) void bscat_k(const int* __restrict__ bcursor,
                                               const unsigned* __restrict__ pairs,
                                               int* __restrict__ col,
                                               int* __restrict__ rowbeg,
                                               int* __restrict__ rowend, int n) {
    __shared__ int hist[256];
    __shared__ int cur[256];
    __shared__ int wsum[4];
    const int b = blockIdx.x;
    const int node0 = b << 8;
    const int t = threadIdx.x;
    const int lane = t & 63, w = t >> 6;

    hist[t] = 0;
    __syncthreads();
    const int pbase = b * PAIR_STRIDE;
    const int tot = bcursor[b];
    for (int i = t; i < tot; i += 256)
        atomicAdd(&hist[pairs[pbase + i] & 255u], 1);
    __syncthreads();

    int v = hist[t];
    int sc = v;
#pragma unroll
    for (int off = 1; off < 64; off <<= 1) {
        int x = __shfl_up(sc, off);
        if (lane >= off) sc += x;
    }
    if (lane == 63) wsum[w] = sc;
    __syncthreads();
    if (t == 0) {
        int a = 0;
#pragma unroll
        for (int j = 0; j < 4; j++) { int tmp = wsum[j]; wsum[j] = a; a += tmp; }
    }
    __syncthreads();
    int excl = sc - v + wsum[w];
    int node = node0 + t;
    int rp = pbase + excl;
    if (node < n) {
        rowbeg[node] = rp;
        rowend[node] = rp + v;
        cur[t] = rp;
    }
    __syncthreads();

    for (int i = t; i < tot; i += 256) {
        unsigned p = pairs[pbase + i];
        int pos = atomicAdd(&cur[p & 255u], 1);
        col[pos] = (int)(p >> 8);
    }
}

// ---------------- MFMA GEMM: H(fp8, permuted) = X @ W, fused s,d ----------------------------
// 128 nodes/block, 512 threads (8 waves), one row-group per wave (R17 config -- the 256-tile
// 2-row-group variant was neutral-to-negative, R18/R19). WT row stride 136 shorts (272B,
// 16B-aligned rows) -> ONE ds_read_b128 per B-fragment (2-way bank alias free, m136).
// XBF16: x rows are bf16 (intermediate layers).
template <int XBF16>
__global__ __launch_bounds__(512) void gemm_k(const void* __restrict__ Xv,
                                              const float* __restrict__ Wm,
                                              const float* __restrict__ asrc,
                                              const float* __restrict__ adst,
                                              unsigned* __restrict__ Hf8,
                                              float* __restrict__ s,
                                              float* __restrict__ d, int n) {
    __shared__ short WT[128 * 136];   // WT[c][k], row stride 136 shorts
    const int t = threadIdx.x;
    const int node0 = blockIdx.x * 128;

    unsigned* WT32 = (unsigned*)WT;
#pragma unroll
    for (int i = 0; i < 16; i++) {
        int item = i * 512 + t;
        int c = item & 127, k2 = item >> 7;
        float va = Wm[(2 * k2) * 128 + c];
        float vb = Wm[(2 * k2 + 1) * 128 + c];
        WT32[c * 68 + k2] = pack2(va, vb);
    }
    __syncthreads();

    const int lane = t & 63, w = t >> 6;
    const int lr = lane & 15, lg = lane >> 4;
    const int row = w * 16 + lr;
    const int node = node0 + row;
    const int nodeA = min(node, n - 1);

    f32x4 acc[8];
#pragma unroll
    for (int ct = 0; ct < 8; ct++) acc[ct] = (f32x4){0.f, 0.f, 0.f, 0.f};

#pragma unroll
    for (int kt = 0; kt < 4; kt++) {
        const int kb = kt * 32 + lg * 8;
        bf16x8 a;
        if (XBF16) {
            const unsigned short* xrow = (const unsigned short*)Xv + (size_t)nodeA * CH;
            a = *(const bf16x8*)&xrow[kb];           // direct bf16 load, no cvt
        } else {
            const float* xrow = (const float*)Xv + (size_t)nodeA * CH;
            const float4 fa = *(const float4*)&xrow[kb];
            const float4 fb = *(const float4*)&xrow[kb + 4];
            a[0] = (short)bf16rne(fa.x); a[1] = (short)bf16rne(fa.y);
            a[2] = (short)bf16rne(fa.z); a[3] = (short)bf16rne(fa.w);
            a[4] = (short)bf16rne(fb.x); a[5] = (short)bf16rne(fb.y);
            a[6] = (short)bf16rne(fb.z); a[7] = (short)bf16rne(fb.w);
        }
#pragma unroll
        for (int ct = 0; ct < 8; ct++) {
            const int cc = ct * 16 + lr;
            bf16x8 bb = *(const bf16x8*)&WT[cc * 136 + kb];   // single b128 read
            acc[ct] = __builtin_amdgcn_mfma_f32_16x16x32_bf16(a, bb, acc[ct], 0, 0, 0);
        }
    }

    float asv[8], adv[8];
#pragma unroll
    for (int ct = 0; ct < 8; ct++) { asv[ct] = asrc[ct * 16 + lr]; adv[ct] = adst[ct * 16 + lr]; }

#pragma unroll
    for (int r = 0; r < 4; r++) {
        const int orow = w * 16 + lg * 4 + r;
        const int onode = node0 + orow;
        float ps = 0.f, pd = 0.f;
#pragma unroll
        for (int ct = 0; ct < 8; ct++) {
            float hv = acc[ct][r];
            ps += hv * asv[ct];
            pd += hv * adv[ct];
        }
        if (onode < n) {
            int w0 = __builtin_amdgcn_cvt_pk_fp8_f32(acc[0][r], acc[1][r], 0, false);
            w0 = __builtin_amdgcn_cvt_pk_fp8_f32(acc[2][r], acc[3][r], w0, true);
            int w1 = __builtin_amdgcn_cvt_pk_fp8_f32(acc[4][r], acc[5][r], 0, false);
            w1 = __builtin_amdgcn_cvt_pk_fp8_f32(acc[6][r], acc[7][r], w1, true);
            uint2 q8; q8.x = (unsigned)w0; q8.y = (unsigned)w1;
            *(uint2*)&Hf8[(size_t)onode * 32 + lr * 2] = q8;
        }
#pragma unroll
        for (int off = 8; off >= 1; off >>= 1) {
            ps += __shfl_xor(ps, off);
            pd += __shfl_xor(pd, off);
        }
        if (lr == 0 && onode < n) { s[onode] = ps; d[onode] = pd; }
    }
}

// ---------------- per-node online-softmax + aggregation + residual ---------------------------
// 4 nodes/wave, sequential order (R14/15 lesson), fp8 H, 4-edge unrolled gather (R18 lesson:
// 8-deep cost VGPR/occupancy more than its MLP bought), packed f32x2 accumulation.
__device__ __forceinline__ void acc_edge(f32x2* o2, const uint2 u, float we) {
    f32x2 w2 = {we, we};
    o2[0] += w2 * __builtin_amdgcn_cvt_pk_f32_fp8(u.x, false);
    o2[1] += w2 * __builtin_amdgcn_cvt_pk_f32_fp8(u.x, true);
    o2[2] += w2 * __builtin_amdgcn_cvt_pk_f32_fp8(u.y, false);
    o2[3] += w2 * __builtin_amdgcn_cvt_pk_f32_fp8(u.y, true);
}

template <int PBF16, int NBF16>
__global__ __launch_bounds__(256) void node_aggr_k(const int* __restrict__ rowbeg,
                                                   const int* __restrict__ rowend,
                                                   const int* __restrict__ col,
                                                   const float* __restrict__ s,
                                                   const float* __restrict__ d,
                                                   const unsigned* __restrict__ Hf8,
                                                   const float* __restrict__ bias,
                                                   const void* __restrict__ x_prev,
                                                   void* __restrict__ x_next, int n) {
    long g = (long)blockIdx.x * 256 + threadIdx.x;
    int node = (int)(g >> 4);
    if (node >= n) return;
    const int tid = threadIdx.x;
    const int sub = tid & 15;
    const int qbase = tid & 48;

    const int beg = rowbeg[node], end = rowend[node];
    const float dn = d[node];
    const float ev_self = leaky(s[node] + dn);

    float m = ev_self;
    float l = 0.f;
    f32x2 o2[4];
#pragma unroll
    for (int j = 0; j < 4; j++) o2[j] = (f32x2){0.f, 0.f};

    for (int j0 = beg; j0 < end; j0 += 16) {
        int cnt = min(16, end - j0);
        int srcv = 0;
        float ev = -INFINITY;
        if (sub < cnt) {
            srcv = col[j0 + sub];
            ev = leaky(s[srcv] + dn);
        }
        float bmax = ev;
#pragma unroll
        for (int off = 8; off >= 1; off >>= 1) bmax = fmaxf(bmax, __shfl_xor(bmax, off));
        float newm = fmaxf(m, bmax);
        float scale = __expf(m - newm);
        f32x2 sc2 = {scale, scale};
        l *= scale;
#pragma unroll
        for (int j = 0; j < 4; j++) o2[j] *= sc2;
        m = newm;
        float wv = (sub < cnt) ? __expf(ev - m) : 0.f;

        // 4-edge unrolled gather: full-exec shuffles with clamped indices (R6 lesson),
        // 4 loads in flight, tail edges duplicate last row with weight 0.
        for (int j = 0; j < cnt; j += 4) {
            int i1 = min(j + 1, cnt - 1), i2 = min(j + 2, cnt - 1), i3 = min(j + 3, cnt - 1);
            int se0 = __shfl(srcv, qbase + j);
            int se1 = __shfl(srcv, qbase + i1);
            int se2 = __shfl(srcv, qbase + i2);
            int se3 = __shfl(srcv, qbase + i3);
            float w0 = __shfl(wv, qbase + j);
            float w1 = __shfl(wv, qbase + i1);
            float w2 = __shfl(wv, qbase + i2);
            float w3 = __shfl(wv, qbase + i3);
            w1 = (j + 1 < cnt) ? w1 : 0.f;
            w2 = (j + 2 < cnt) ? w2 : 0.f;
            w3 = (j + 3 < cnt) ? w3 : 0.f;
            const uint2 u0 = *(const uint2*)&Hf8[(size_t)se0 * 32 + sub * 2];
            const uint2 u1 = *(const uint2*)&Hf8[(size_t)se1 * 32 + sub * 2];
            const uint2 u2 = *(const uint2*)&Hf8[(size_t)se2 * 32 + sub * 2];
            const uint2 u3 = *(const uint2*)&Hf8[(size_t)se3 * 32 + sub * 2];
            l += w0 + w1 + w2 + w3;
            acc_edge(o2, u0, w0);
            acc_edge(o2, u1, w1);
            acc_edge(o2, u2, w2);
            acc_edge(o2, u3, w3);
        }
    }

    // self loop (fp8, same as edges)
    float wself = __expf(ev_self - m);
    l += wself;
    const uint2 us = *(const uint2*)&Hf8[(size_t)node * 32 + sub * 2];
    acc_edge(o2, us, wself);

    float inv = 1.f / (l + EPS_D);
    const long rowb = (long)node * CH;
#pragma unroll
    for (int k = 0; k < 8; k++) {
        int c = k * 16 + sub;   // permuted: o2[k>>1][k&1] is channel k*16+sub
        float ov = o2[k >> 1][k & 1];
        float xv = PBF16 ? bf16tof(((const unsigned short*)x_prev)[rowb + c])
                         : ((const float*)x_prev)[rowb + c];
        float r = xv + sigm(ov * inv + bias[c]);
        if (NBF16)
            ((unsigned short*)x_next)[rowb + c] = (unsigned short)bf16rne(r);
        else
            ((float*)x_next)[rowb + c] = r;
    }
}

extern "C" void kernel_launch(void* const* d_in, const int* in_sizes, int n_in,
                              void* d_out, int out_size, void* d_ws, size_t ws_size,
                              hipStream_t stream) {
    const float* x_in = (const float*)d_in[0];
    const int* EI = (const int*)d_in[1];
    const float* Ws_all = (const float*)d_in[2];
    const float* asrc_all = (const float*)d_in[3];
    const float* adst_all = (const float*)d_in[4];
    const float* bias_all = (const float*)d_in[5];
    float* out = (float*)d_out;

    const int n = in_sizes[0] / CH;        // 100000
    const int ne = in_sizes[1] / 2;        // 1600000
    const long NC = (long)n * CH;
    const int nbuck = (n + 255) >> 8;

    unsigned* hf8 = (unsigned*)d_ws;                 // NC/4 u32 (fp8 H)
    float* s = (float*)(hf8 + NC / 4);
    float* dd = s + n;
    unsigned short* xb0 = (unsigned short*)(dd + n); // NC bf16
    unsigned short* xb1 = xb0 + NC;                  // NC bf16
    int* rowbeg = (int*)(xb1 + NC);
    int* rowend = rowbeg + n;
    int* bcursor = rowend + n;
    int* colv = bcursor + nbuck;                     // nbuck * PAIR_STRIDE
    unsigned* pairs = (unsigned*)(colv + nbuck * PAIR_STRIDE);  // nbuck * PAIR_STRIDE

    // --- CSR build (padded col regions; rowbeg/rowend from bscat) ---
    hipMemsetAsync(bcursor, 0, (size_t)nbuck * sizeof(int), stream);
    bin_k<<<(ne + BIN_CHUNK - 1) / BIN_CHUNK, 256, 0, stream>>>(EI, bcursor, pairs, ne, nbuck);
    bscat_k<<<nbuck, 256, 0, stream>>>(bcursor, pairs, colv, rowbeg, rowend, n);

    const int gG = (n + 127) / 128;
    const int gA = (int)(((long)n * 16 + 255) / 256);

    // layer 0: f32 in -> bf16 out
    gemm_k<0><<<gG, 512, 0, stream>>>(x_in, Ws_all, asrc_all, adst_all, hf8, s, dd, n);
    node_aggr_k<0, 1><<<gA, 256, 0, stream>>>(rowbeg, rowend, colv, s, dd, hf8,
                                              bias_all, x_in, xb0, n);
    // layer 1: bf16 in -> bf16 out
    gemm_k<1><<<gG, 512, 0, stream>>>(xb0, Ws_all + (size_t)CH * CH, asrc_all + CH,
                                      adst_all + CH, hf8, s, dd, n);
    node_aggr_k<1, 1><<<gA, 256, 0, stream>>>(rowbeg, rowend, colv, s, dd, hf8,
                                              bias_all + CH, xb0, xb1, n);
    // layer 2: bf16 in -> f32 out (final)
    gemm_k<1><<<gG, 512, 0, stream>>>(xb1, Ws_all + (size_t)2 * CH * CH, asrc_all + 2 * CH,
                                      adst_all + 2 * CH, hf8, s, dd, n);
    node_aggr_k<1, 0><<<gA, 256, 0, stream>>>(rowbeg, rowend, colv, s, dd, hf8,
                                              bias_all + 2 * CH, xb1, out, n);
}